// Round 6
// baseline (378.373 us; speedup 1.0000x reference)
//
#include <hip/hip_runtime.h>

#define S_TOTAL 17064
#define NB 16
#define NC 80
#define FOCAL_BLOCKS_PER_B 169                    // 125+32+8+3+1 chunks of 2048 quads
#define FOCAL_BLOCKS (FOCAL_BLOCKS_PER_B * NB)    // 2704
#define PB_BLOCKS_PER_B 17                        // ceil(4266/256)
#define PB_BLOCKS (PB_BLOCKS_PER_B * NB)          // 272
#define TOTAL_BLOCKS (FOCAL_BLOCKS + PB_BLOCKS)   // 2976

typedef float vfloat4 __attribute__((ext_vector_type(4)));

struct Ptrs {
    const float* cls[5];
    const float* cnt[5];
    const float* reg[5];
    const float* cnt_t;   // [B,S,1]
    const float* reg_t;   // [B,S,4]
    const int*   cls_t;   // [B,S,1]
    float*       ws;      // [0:16) cls, [16:32) cnt, [32:48) reg, [48:64) pos, [64] counter
    float*       out;
};

__device__ __forceinline__ float focal_term(float x, bool o) {
    const float xs = o ? x : -x;            // p_t = sigmoid(xs)
    const float af = o ? 0.25f : 0.75f;
    const float em = __expf(-xs);
    const float pt = 1.0f / (1.0f + em);
    const float q  = em * pt;               // 1 - p_t
    return af * q * q * __logf(1.0f + em);  // -af*(1-pt)^2*log(pt)
}

__device__ __forceinline__ float giou_term(float pl, float pt_, float pr, float pb,
                                           float tl, float tt, float tr, float tb) {
    const float overlap = fmaxf(fminf(pr, tr) + fminf(pl, tl), 0.0f) *
                          fmaxf(fminf(pb, tb) + fminf(pt_, tt), 0.0f);
    const float area1 = (pr + pl) * (pb + pt_);
    const float area2 = (tr + tl) * (tb + tt);
    const float uni = area1 + area2 - overlap;
    const float iou = overlap / uni;
    const float ga = fmaxf(fmaxf(pr, tr) + fmaxf(pl, tl), 0.0f) *
                     fmaxf(fmaxf(pb, tb) + fmaxf(pt_, tt), 0.0f);
    const float giou = iou - (ga - uni) / fmaxf(ga, 1e-10f);
    return 1.0f - giou;
}

__device__ __forceinline__ float bce_term(float x, float t) {
    return fmaxf(x, 0.0f) - x * t + __logf(1.0f + __expf(-fabsf(x)));
}

// One 2048-quad chunk of the (class x space) plane of one (batch, level).
// Thread does 8 strided quads; all 16 loads issued before any compute.
template<int HW, int NQ, int OFF>
__device__ __forceinline__ float focal_chunk(const float* __restrict__ clsl,
                                             const int* __restrict__ cls_t,
                                             int b, int chunk, int tid) {
    constexpr int LIM = NC * NQ;                  // quads in this (b,level) slab
    const int qb = chunk * 2048 + tid;
    const float* cb = clsl + (size_t)b * NC * HW;
    const int*   tb = cls_t + b * S_TOTAL + OFF;

    vfloat4 v[8];
    int4    tq[8];
    int     cidx[8];
    bool    val[8];
    #pragma unroll
    for (int i = 0; i < 8; ++i) {
        int idx = qb + i * 256;
        val[i] = (idx < LIM);
        idx = val[i] ? idx : 0;                   // clamp: keep loads in-bounds
        const int c  = idx / NQ;                  // constant divisor -> magic mul
        const int sq = idx - c * NQ;
        cidx[i] = c;
        v[i]  = *(const vfloat4*)(cb + (size_t)(c * HW + 4 * sq));
        tq[i] = *(const int4*)(tb + 4 * sq);
    }
    float a0 = 0.f, a1 = 0.f, a2 = 0.f, a3 = 0.f;
    #pragma unroll
    for (int i = 0; i < 8; ++i) {
        if (val[i]) {
            const int cp1 = cidx[i] + 1;
            a0 += focal_term(v[i].x, tq[i].x == cp1);
            a1 += focal_term(v[i].y, tq[i].y == cp1);
            a2 += focal_term(v[i].z, tq[i].z == cp1);
            a3 += focal_term(v[i].w, tq[i].w == cp1);
        }
    }
    return (a0 + a1) + (a2 + a3);
}

__global__ __launch_bounds__(256, 4) void fcos_main(Ptrs p) {
    const int bid = blockIdx.x;
    const int tid = threadIdx.x;

    float cls_acc = 0.f, cnt_acc = 0.f, reg_acc = 0.f, pos_acc = 0.f;
    int b;

    if (bid < FOCAL_BLOCKS) {
        b = bid / FOCAL_BLOCKS_PER_B;
        const int r = bid - b * FOCAL_BLOCKS_PER_B;
        if (r < 125)      cls_acc = focal_chunk<12800, 3200,     0>(p.cls[0], p.cls_t, b, r,       tid);
        else if (r < 157) cls_acc = focal_chunk< 3200,  800, 12800>(p.cls[1], p.cls_t, b, r - 125, tid);
        else if (r < 165) cls_acc = focal_chunk<  800,  200, 16000>(p.cls[2], p.cls_t, b, r - 157, tid);
        else if (r < 168) cls_acc = focal_chunk<  208,   52, 16800>(p.cls[3], p.cls_t, b, r - 165, tid);
        else              cls_acc = focal_chunk<   56,   14, 17008>(p.cls[4], p.cls_t, b, r - 168, tid);
    } else {
        const int pb = bid - FOCAL_BLOCKS;
        b = pb / PB_BLOCKS_PER_B;
        const int chunk = pb - b * PB_BLOCKS_PER_B;
        const int fq = chunk * 256 + tid;         // quad within image, 0..4351

        int lvl, qbase, hw, off;
        if (fq < 3200)      { lvl = 0; qbase = 0;    hw = 12800; off = 0;     }
        else if (fq < 4000) { lvl = 1; qbase = 3200; hw = 3200;  off = 12800; }
        else if (fq < 4200) { lvl = 2; qbase = 4000; hw = 800;   off = 16000; }
        else if (fq < 4252) { lvl = 3; qbase = 4200; hw = 208;   off = 16800; }
        else                { lvl = 4; qbase = 4252; hw = 56;    off = 17008; }

        if (fq < 4266) {
            const int s0  = (fq - qbase) << 2;
            const int gs0 = b * S_TOTAL + off + s0;
            const float4 xc  = *(const float4*)(p.cnt[lvl] + (size_t)(b * hw + s0));
            const float4 tC  = *(const float4*)(p.cnt_t + gs0);
            const float* rp  = p.reg[lvl] + (size_t)(b * 4 * hw + s0);
            const float4 pl  = *(const float4*)(rp);
            const float4 pt_ = *(const float4*)(rp + (size_t)hw);
            const float4 pr  = *(const float4*)(rp + (size_t)(2 * hw));
            const float4 pb_ = *(const float4*)(rp + (size_t)(3 * hw));
            const float4 t0  = *(const float4*)(p.reg_t + (size_t)(gs0 + 0) * 4);
            const float4 t1  = *(const float4*)(p.reg_t + (size_t)(gs0 + 1) * 4);
            const float4 t2  = *(const float4*)(p.reg_t + (size_t)(gs0 + 2) * 4);
            const float4 t3  = *(const float4*)(p.reg_t + (size_t)(gs0 + 3) * 4);

            const float m0 = (tC.x > -1.0f) ? 1.0f : 0.0f;
            const float m1 = (tC.y > -1.0f) ? 1.0f : 0.0f;
            const float m2 = (tC.z > -1.0f) ? 1.0f : 0.0f;
            const float m3 = (tC.w > -1.0f) ? 1.0f : 0.0f;
            pos_acc = m0 + m1 + m2 + m3;
            cnt_acc = bce_term(xc.x, tC.x) * m0 + bce_term(xc.y, tC.y) * m1 +
                      bce_term(xc.z, tC.z) * m2 + bce_term(xc.w, tC.w) * m3;
            reg_acc = giou_term(pl.x, pt_.x, pr.x, pb_.x, t0.x, t0.y, t0.z, t0.w) * m0 +
                      giou_term(pl.y, pt_.y, pr.y, pb_.y, t1.x, t1.y, t1.z, t1.w) * m1 +
                      giou_term(pl.z, pt_.z, pr.z, pb_.z, t2.x, t2.y, t2.z, t2.w) * m2 +
                      giou_term(pl.w, pt_.w, pr.w, pb_.w, t3.x, t3.y, t3.z, t3.w) * m3;
        }
    }

    // ---- block reduction ----
    #pragma unroll
    for (int d = 32; d; d >>= 1) {
        cls_acc += __shfl_down(cls_acc, d);
        cnt_acc += __shfl_down(cnt_acc, d);
        reg_acc += __shfl_down(reg_acc, d);
        pos_acc += __shfl_down(pos_acc, d);
    }

    __shared__ float red[4][4];
    const int wave = tid >> 6;
    const int lane = tid & 63;
    if (lane == 0) {
        red[0][wave] = cls_acc;
        red[1][wave] = cnt_acc;
        red[2][wave] = reg_acc;
        red[3][wave] = pos_acc;
    }
    __syncthreads();
    if (tid == 0) {
        atomicAdd(&p.ws[b], red[0][0] + red[0][1] + red[0][2] + red[0][3]);
        if (bid >= FOCAL_BLOCKS) {
            atomicAdd(&p.ws[16 + b], red[1][0] + red[1][1] + red[1][2] + red[1][3]);
            atomicAdd(&p.ws[32 + b], red[2][0] + red[2][1] + red[2][2] + red[2][3]);
            atomicAdd(&p.ws[48 + b], red[3][0] + red[3][1] + red[3][2] + red[3][3]);
        }
    }

    // ---- last-block finalize ----
    __shared__ int is_last;
    if (tid == 0) {
        __threadfence();
        const int old = __hip_atomic_fetch_add((int*)(p.ws + 64), 1,
                            __ATOMIC_ACQ_REL, __HIP_MEMORY_SCOPE_AGENT);
        is_last = (old == TOTAL_BLOCKS - 1) ? 1 : 0;
    }
    __syncthreads();
    if (is_last && tid < 64) {
        __threadfence();
        float l0 = 0.f, l1 = 0.f, l2 = 0.f;
        if (tid < NB) {
            const float np = fmaxf(__hip_atomic_load(&p.ws[48 + tid],
                __ATOMIC_RELAXED, __HIP_MEMORY_SCOPE_AGENT), 1.0f);
            l0 = __hip_atomic_load(&p.ws[tid],
                __ATOMIC_RELAXED, __HIP_MEMORY_SCOPE_AGENT) / np;
            l1 = __hip_atomic_load(&p.ws[16 + tid],
                __ATOMIC_RELAXED, __HIP_MEMORY_SCOPE_AGENT) / np;
            l2 = __hip_atomic_load(&p.ws[32 + tid],
                __ATOMIC_RELAXED, __HIP_MEMORY_SCOPE_AGENT) / np;
        }
        #pragma unroll
        for (int d = 32; d; d >>= 1) {
            l0 += __shfl_down(l0, d);
            l1 += __shfl_down(l1, d);
            l2 += __shfl_down(l2, d);
        }
        if (tid == 0) {
            l0 *= (1.0f / NB);
            l1 *= (1.0f / NB);
            l2 *= (1.0f / NB);
            p.out[0] = l0;
            p.out[1] = l1;
            p.out[2] = l2;
            p.out[3] = l0 + l1 + l2;
        }
    }
}

extern "C" void kernel_launch(void* const* d_in, const int* in_sizes, int n_in,
                              void* d_out, int out_size, void* d_ws, size_t ws_size,
                              hipStream_t stream) {
    Ptrs p;
    for (int i = 0; i < 5; ++i) {
        p.cls[i] = (const float*)d_in[3 * i + 0];
        p.cnt[i] = (const float*)d_in[3 * i + 1];
        p.reg[i] = (const float*)d_in[3 * i + 2];
    }
    p.cnt_t = (const float*)d_in[15];
    p.reg_t = (const float*)d_in[16];
    p.cls_t = (const int*)  d_in[17];
    p.ws    = (float*)d_ws;
    p.out   = (float*)d_out;

    (void)hipMemsetAsync(d_ws, 0, 68 * sizeof(float), stream);  // sums + counter

    fcos_main<<<dim3(TOTAL_BLOCKS, 1, 1), 256, 0, stream>>>(p);
}

// Round 7
// 261.498 us; speedup vs baseline: 1.4469x; 1.4469x over previous
//
#include <hip/hip_runtime.h>

#define S_TOTAL 17064
#define NB 16
#define NC 80
#define QPB 4266                                  // location-quads per image
#define NXQ 17                                    // 256-quad chunks per image
#define NCG 5                                     // class groups of 16
#define FOCAL_BLOCKS (NB * NXQ * NCG)             // 1360
#define PB_BLOCKS (NB * NXQ)                      // 272
#define TOTAL_BLOCKS (FOCAL_BLOCKS + PB_BLOCKS)   // 1632

typedef float vfloat4 __attribute__((ext_vector_type(4)));

struct Ptrs {
    const float* cls[5];
    const float* cnt[5];
    const float* reg[5];
    const float* cnt_t;   // [B,S,1]
    const float* reg_t;   // [B,S,4]
    const int*   cls_t;   // [B,S,1]
    float*       ws;      // [0:16) cls, [16:32) cnt, [32:48) reg, [48:64) pos, [64] counter
    float*       out;
};

__device__ __forceinline__ float focal_term(float x, bool o) {
    const float xs = o ? x : -x;            // p_t = sigmoid(xs)
    const float af = o ? 0.25f : 0.75f;
    const float em = __expf(-xs);
    const float pt = 1.0f / (1.0f + em);
    const float q  = em * pt;               // 1 - p_t
    return af * q * q * __logf(1.0f + em);  // -af*(1-pt)^2*log(pt)
}

__device__ __forceinline__ float giou_term(float pl, float pt_, float pr, float pb,
                                           float tl, float tt, float tr, float tb) {
    const float overlap = fmaxf(fminf(pr, tr) + fminf(pl, tl), 0.0f) *
                          fmaxf(fminf(pb, tb) + fminf(pt_, tt), 0.0f);
    const float area1 = (pr + pl) * (pb + pt_);
    const float area2 = (tr + tl) * (tb + tt);
    const float uni = area1 + area2 - overlap;
    const float iou = overlap / uni;
    const float ga = fmaxf(fmaxf(pr, tr) + fmaxf(pl, tl), 0.0f) *
                     fmaxf(fmaxf(pb, tb) + fmaxf(pt_, tt), 0.0f);
    const float giou = iou - (ga - uni) / fmaxf(ga, 1e-10f);
    return 1.0f - giou;
}

__device__ __forceinline__ float bce_term(float x, float t) {
    return fmaxf(x, 0.0f) - x * t + __logf(1.0f + __expf(-fabsf(x)));
}

__global__ __launch_bounds__(256) void fcos_main(Ptrs p) {
    const int bid = blockIdx.x;
    const int tid = threadIdx.x;

    float cls_acc = 0.f, cnt_acc = 0.f, reg_acc = 0.f, pos_acc = 0.f;
    int b;

    if (bid < FOCAL_BLOCKS) {
        b = bid / (NXQ * NCG);
        const int r     = bid - b * (NXQ * NCG);
        const int cg    = r / NXQ;                // class group 0..4
        const int chunk = r - cg * NXQ;           // quad chunk 0..16
        const int fq    = chunk * 256 + tid;      // quad within image

        int lvl, qbase, hw, off;
        if (fq < 3200)      { lvl = 0; qbase = 0;    hw = 12800; off = 0;     }
        else if (fq < 4000) { lvl = 1; qbase = 3200; hw = 3200;  off = 12800; }
        else if (fq < 4200) { lvl = 2; qbase = 4000; hw = 800;   off = 16000; }
        else if (fq < 4252) { lvl = 3; qbase = 4200; hw = 208;   off = 16800; }
        else                { lvl = 4; qbase = 4252; hw = 56;    off = 17008; }
        const bool active = (fq < QPB);

        const int s0  = active ? ((fq - qbase) << 2) : 0;   // clamp keeps all loads in-bounds
        const int gs0 = b * S_TOTAL + off + s0;
        const int c0  = cg * 16;
        const float* cp = p.cls[lvl] + (size_t)((b * NC + c0) * hw + s0);

        // ---- 16 loads issued before any compute: 16 KB/wave in flight ----
        vfloat4 A[8], B[8];
        #pragma unroll
        for (int j = 0; j < 8; ++j)
            A[j] = *(const vfloat4*)(cp + (size_t)(j * hw));
        #pragma unroll
        for (int j = 0; j < 8; ++j)
            B[j] = *(const vfloat4*)(cp + (size_t)((8 + j) * hw));
        const int4 tq = *(const int4*)(p.cls_t + gs0);

        float a0 = 0.f, a1 = 0.f, a2 = 0.f, a3 = 0.f;
        #pragma unroll
        for (int j = 0; j < 8; ++j) {
            const int cp1 = c0 + j + 1;
            a0 += focal_term(A[j].x, tq.x == cp1);
            a1 += focal_term(A[j].y, tq.y == cp1);
            a2 += focal_term(A[j].z, tq.z == cp1);
            a3 += focal_term(A[j].w, tq.w == cp1);
        }
        #pragma unroll
        for (int j = 0; j < 8; ++j) {
            const int cp1 = c0 + 8 + j + 1;
            a0 += focal_term(B[j].x, tq.x == cp1);
            a1 += focal_term(B[j].y, tq.y == cp1);
            a2 += focal_term(B[j].z, tq.z == cp1);
            a3 += focal_term(B[j].w, tq.w == cp1);
        }
        cls_acc = active ? ((a0 + a1) + (a2 + a3)) : 0.f;
    } else {
        const int pb = bid - FOCAL_BLOCKS;
        b = pb / NXQ;
        const int chunk = pb - b * NXQ;
        const int fq = chunk * 256 + tid;

        int lvl, qbase, hw, off;
        if (fq < 3200)      { lvl = 0; qbase = 0;    hw = 12800; off = 0;     }
        else if (fq < 4000) { lvl = 1; qbase = 3200; hw = 3200;  off = 12800; }
        else if (fq < 4200) { lvl = 2; qbase = 4000; hw = 800;   off = 16000; }
        else if (fq < 4252) { lvl = 3; qbase = 4200; hw = 208;   off = 16800; }
        else                { lvl = 4; qbase = 4252; hw = 56;    off = 17008; }

        if (fq < QPB) {
            const int s0  = (fq - qbase) << 2;
            const int gs0 = b * S_TOTAL + off + s0;
            const float4 xc  = *(const float4*)(p.cnt[lvl] + (size_t)(b * hw + s0));
            const float4 tC  = *(const float4*)(p.cnt_t + gs0);
            const float* rp  = p.reg[lvl] + (size_t)(b * 4 * hw + s0);
            const float4 pl  = *(const float4*)(rp);
            const float4 pt_ = *(const float4*)(rp + (size_t)hw);
            const float4 pr  = *(const float4*)(rp + (size_t)(2 * hw));
            const float4 pb_ = *(const float4*)(rp + (size_t)(3 * hw));
            const float4 t0  = *(const float4*)(p.reg_t + (size_t)(gs0 + 0) * 4);
            const float4 t1  = *(const float4*)(p.reg_t + (size_t)(gs0 + 1) * 4);
            const float4 t2  = *(const float4*)(p.reg_t + (size_t)(gs0 + 2) * 4);
            const float4 t3  = *(const float4*)(p.reg_t + (size_t)(gs0 + 3) * 4);

            const float m0 = (tC.x > -1.0f) ? 1.0f : 0.0f;
            const float m1 = (tC.y > -1.0f) ? 1.0f : 0.0f;
            const float m2 = (tC.z > -1.0f) ? 1.0f : 0.0f;
            const float m3 = (tC.w > -1.0f) ? 1.0f : 0.0f;
            pos_acc = m0 + m1 + m2 + m3;
            cnt_acc = bce_term(xc.x, tC.x) * m0 + bce_term(xc.y, tC.y) * m1 +
                      bce_term(xc.z, tC.z) * m2 + bce_term(xc.w, tC.w) * m3;
            reg_acc = giou_term(pl.x, pt_.x, pr.x, pb_.x, t0.x, t0.y, t0.z, t0.w) * m0 +
                      giou_term(pl.y, pt_.y, pr.y, pb_.y, t1.x, t1.y, t1.z, t1.w) * m1 +
                      giou_term(pl.z, pt_.z, pr.z, pb_.z, t2.x, t2.y, t2.z, t2.w) * m2 +
                      giou_term(pl.w, pt_.w, pr.w, pb_.w, t3.x, t3.y, t3.z, t3.w) * m3;
        }
    }

    // ---- block reduction ----
    #pragma unroll
    for (int d = 32; d; d >>= 1) {
        cls_acc += __shfl_down(cls_acc, d);
        cnt_acc += __shfl_down(cnt_acc, d);
        reg_acc += __shfl_down(reg_acc, d);
        pos_acc += __shfl_down(pos_acc, d);
    }

    __shared__ float red[4][4];
    const int wave = tid >> 6;
    const int lane = tid & 63;
    if (lane == 0) {
        red[0][wave] = cls_acc;
        red[1][wave] = cnt_acc;
        red[2][wave] = reg_acc;
        red[3][wave] = pos_acc;
    }
    __syncthreads();
    if (tid == 0) {
        atomicAdd(&p.ws[b], red[0][0] + red[0][1] + red[0][2] + red[0][3]);
        if (bid >= FOCAL_BLOCKS) {
            atomicAdd(&p.ws[16 + b], red[1][0] + red[1][1] + red[1][2] + red[1][3]);
            atomicAdd(&p.ws[32 + b], red[2][0] + red[2][1] + red[2][2] + red[2][3]);
            atomicAdd(&p.ws[48 + b], red[3][0] + red[3][1] + red[3][2] + red[3][3]);
        }
    }

    // ---- last-block finalize ----
    __shared__ int is_last;
    if (tid == 0) {
        __threadfence();
        const int old = __hip_atomic_fetch_add((int*)(p.ws + 64), 1,
                            __ATOMIC_ACQ_REL, __HIP_MEMORY_SCOPE_AGENT);
        is_last = (old == TOTAL_BLOCKS - 1) ? 1 : 0;
    }
    __syncthreads();
    if (is_last && tid < 64) {
        __threadfence();
        float l0 = 0.f, l1 = 0.f, l2 = 0.f;
        if (tid < NB) {
            const float np = fmaxf(__hip_atomic_load(&p.ws[48 + tid],
                __ATOMIC_RELAXED, __HIP_MEMORY_SCOPE_AGENT), 1.0f);
            l0 = __hip_atomic_load(&p.ws[tid],
                __ATOMIC_RELAXED, __HIP_MEMORY_SCOPE_AGENT) / np;
            l1 = __hip_atomic_load(&p.ws[16 + tid],
                __ATOMIC_RELAXED, __HIP_MEMORY_SCOPE_AGENT) / np;
            l2 = __hip_atomic_load(&p.ws[32 + tid],
                __ATOMIC_RELAXED, __HIP_MEMORY_SCOPE_AGENT) / np;
        }
        #pragma unroll
        for (int d = 32; d; d >>= 1) {
            l0 += __shfl_down(l0, d);
            l1 += __shfl_down(l1, d);
            l2 += __shfl_down(l2, d);
        }
        if (tid == 0) {
            l0 *= (1.0f / NB);
            l1 *= (1.0f / NB);
            l2 *= (1.0f / NB);
            p.out[0] = l0;
            p.out[1] = l1;
            p.out[2] = l2;
            p.out[3] = l0 + l1 + l2;
        }
    }
}

extern "C" void kernel_launch(void* const* d_in, const int* in_sizes, int n_in,
                              void* d_out, int out_size, void* d_ws, size_t ws_size,
                              hipStream_t stream) {
    Ptrs p;
    for (int i = 0; i < 5; ++i) {
        p.cls[i] = (const float*)d_in[3 * i + 0];
        p.cnt[i] = (const float*)d_in[3 * i + 1];
        p.reg[i] = (const float*)d_in[3 * i + 2];
    }
    p.cnt_t = (const float*)d_in[15];
    p.reg_t = (const float*)d_in[16];
    p.cls_t = (const int*)  d_in[17];
    p.ws    = (float*)d_ws;
    p.out   = (float*)d_out;

    (void)hipMemsetAsync(d_ws, 0, 68 * sizeof(float), stream);  // sums + counter

    fcos_main<<<dim3(TOTAL_BLOCKS, 1, 1), 256, 0, stream>>>(p);
}